// Round 6
// baseline (589.574 us; speedup 1.0000x reference)
//
#include <hip/hip_runtime.h>
#include <math.h>

// Graph VAE forward, bf16 edition.
//   SpMM at the narrow dim (gconv2 does GEMM first), pull-style padded CSR.
//   All feature-map intermediates bf16 (fp32 accumulate):
//     features->xb --spmm--> agg1 --MFMA--> h(bf16, in d_out)
//     --MFMA--> hw --spmm+epi--> mean/logvar(fp32 out), z(bf16)
//     --spmm--> aggz --MFMA--> recon(fp32 out)
//   CSR build: XCD-sliced (slice(n)=(n>>11)&7, block b owns slice b&7) so all
//   stores/atomics for an ebuf/cnt line issue from one L2.
//   DETERMINISM: atomic slot order is race-dependent; bf16 rounding ties
//   amplify reorder noise into full-ULP output flips across graph replays
//   (round-5 post-timing failure). k_sortel bitonic-sorts each node's slot
//   list -> bit-identical results on every replay.

#define MAXD 64   // padded per-node in-edge capacity; deg ~ Poisson(16)
#define SL(n) (((n) >> 11) & 7)

typedef short short8 __attribute__((ext_vector_type(8)));
typedef float f32x4 __attribute__((ext_vector_type(4)));

__device__ __forceinline__ unsigned short f2bf(float f) {
  union { float f; unsigned u; } c; c.f = f;
  unsigned r = c.u + 0x7FFF + ((c.u >> 16) & 1);   // RNE
  return (unsigned short)(r >> 16);
}
__device__ __forceinline__ float bf2f(unsigned short b) {
  return __builtin_bit_cast(float, (unsigned)b << 16);
}

// ---- build padded CSR (by dst) + out-degree histogram, XCD-sliced -----
__global__ __launch_bounds__(256) void k_hist_sl(const int* __restrict__ src,
    const int* __restrict__ dst, int* __restrict__ degout, int* __restrict__ cnt,
    int* __restrict__ ebuf, int E) {
  int sl = blockIdx.x & 7;
  int t = (blockIdx.x >> 3) * 256 + threadIdx.x;
  int e0 = t * 4;
  if (e0 + 4 <= E) {
    int4 s4 = *(const int4*)(src + e0);
    int4 d4 = *(const int4*)(dst + e0);
    if (SL(s4.x) == sl) atomicAdd(&degout[s4.x], 1);
    if (SL(s4.y) == sl) atomicAdd(&degout[s4.y], 1);
    if (SL(s4.z) == sl) atomicAdd(&degout[s4.z], 1);
    if (SL(s4.w) == sl) atomicAdd(&degout[s4.w], 1);
    if (SL(d4.x) == sl) { int p = atomicAdd(&cnt[d4.x], 1); if (p < MAXD) ebuf[d4.x * MAXD + p] = s4.x; }
    if (SL(d4.y) == sl) { int p = atomicAdd(&cnt[d4.y], 1); if (p < MAXD) ebuf[d4.y * MAXD + p] = s4.y; }
    if (SL(d4.z) == sl) { int p = atomicAdd(&cnt[d4.z], 1); if (p < MAXD) ebuf[d4.z * MAXD + p] = s4.z; }
    if (SL(d4.w) == sl) { int p = atomicAdd(&cnt[d4.w], 1); if (p < MAXD) ebuf[d4.w * MAXD + p] = s4.w; }
  } else {
    for (int e = e0; e < E; e++) {
      int s = src[e], d = dst[e];
      if (SL(s) == sl) atomicAdd(&degout[s], 1);
      if (SL(d) == sl) { int p = atomicAdd(&cnt[d], 1); if (p < MAXD) ebuf[d * MAXD + p] = s; }
    }
  }
}

// ---- bitonic-sort each node's slot list (determinism) -----------------
__global__ __launch_bounds__(256) void k_sortel(int* __restrict__ ebuf,
    const int* __restrict__ cnt, int N) {
  int lane = threadIdx.x & 63;
  int v = blockIdx.x * 4 + (threadIdx.x >> 6);
  if (v >= N) return;
  v = __builtin_amdgcn_readfirstlane(v);
  int c = cnt[v]; c = c < MAXD ? c : MAXD;
  int* el = ebuf + (size_t)v * MAXD;
  int val = (lane < c) ? el[lane] : 0x7FFFFFFF;
  #pragma unroll
  for (int k = 2; k <= 64; k <<= 1) {
    #pragma unroll
    for (int j = k >> 1; j >= 1; j >>= 1) {
      int other = __shfl_xor(val, j);
      bool lower = (lane & j) == 0;
      bool asc = (lane & k) == 0;
      int mn = min(val, other), mx = max(val, other);
      val = (lower == asc) ? mn : mx;
    }
  }
  if (lane < c) el[lane] = val;
}

__global__ __launch_bounds__(256) void k_scale(const int* __restrict__ degout,
    const int* __restrict__ cnt, float* __restrict__ sout,
    float* __restrict__ sin_, int N) {
  int i = blockIdx.x * 256 + threadIdx.x;
  if (i >= N) return;
  int dO = degout[i]; if (dO < 1) dO = 1;
  int dI = cnt[i];    if (dI < 1) dI = 1;
  sout[i] = rsqrtf((float)dO);
  sin_[i] = rsqrtf((float)dI);
}

// ---- fp32 -> bf16 row-major convert (features) ------------------------
__global__ __launch_bounds__(256) void k_cvt(const float* __restrict__ in,
    unsigned short* __restrict__ out, int n) {
  int i = (blockIdx.x * 256 + threadIdx.x) * 4;
  if (i >= n) return;
  float4 f = *(const float4*)(in + i);
  unsigned lo = (unsigned)f2bf(f.x) | ((unsigned)f2bf(f.y) << 16);
  unsigned hi = (unsigned)f2bf(f.z) | ((unsigned)f2bf(f.w) << 16);
  uint2 o; o.x = lo; o.y = hi;
  *(uint2*)(out + i) = o;
}

// ---- repack W[K][OC] fp32 -> bf16 B-fragment layout -------------------
template <int K, int OC>
__global__ __launch_bounds__(256) void k_wrepack(const float* __restrict__ W,
    short* __restrict__ Wp) {
  constexpr int KC = K / 32;
  constexpr int TOT = (OC / 16) * KC * 64;
  int t = blockIdx.x * 256 + threadIdx.x;
  if (t >= TOT) return;
  int lane = t & 63;
  int kc = (t >> 6) % KC;
  int nt = t / (KC * 64);
  int n = nt * 16 + (lane & 15);
  int k0 = kc * 32 + ((lane >> 4) * 8);
  short8 v;
  #pragma unroll
  for (int j = 0; j < 8; j++) v[j] = (short)f2bf(W[(size_t)(k0 + j) * OC + n]);
  *(short8*)(Wp + (size_t)t * 8) = v;
}

// ---- MFMA GEMM: C[N,OC] = A[N,K](bf16) @ Wp(frag bf16) (+bias, relu) --
template <int K, int OC, bool RELU, bool BIAS, bool OUTBF16>
__global__ __launch_bounds__(256) void k_gemm_mfma(
    const unsigned short* __restrict__ A, const short* __restrict__ Wp,
    const float* __restrict__ bias, void* __restrict__ Cout, int N) {
  constexpr int KC = K / 32;
  constexpr int NT = OC / 16;
  int lane = threadIdx.x & 63;
  int wv = threadIdx.x >> 6;
  int m0 = (blockIdx.x * 4 + wv) * 16;
  if (m0 >= N) return;
  int mrow = m0 + (lane & 15);
  if (mrow >= N) mrow = N - 1;          // clamp loads; stores predicated
  int q = lane >> 4;
  short8 av[KC];
  #pragma unroll
  for (int kc = 0; kc < KC; kc++)
    av[kc] = *(const short8*)(A + (size_t)mrow * K + kc * 32 + q * 8);
  int col0 = lane & 15;
  int rbase = m0 + q * 4;               // C/D: col=lane&15, row=(lane>>4)*4+r
  #pragma unroll
  for (int nt = 0; nt < NT; nt++) {
    f32x4 acc = {0.f, 0.f, 0.f, 0.f};
    #pragma unroll
    for (int kc = 0; kc < KC; kc++) {
      short8 bv = *(const short8*)(Wp + ((size_t)(nt * KC + kc) * 64 + lane) * 8);
      acc = __builtin_amdgcn_mfma_f32_16x16x32_bf16(av[kc], bv, acc, 0, 0, 0);
    }
    int col = nt * 16 + col0;
    float bb = BIAS ? bias[col] : 0.f;
    #pragma unroll
    for (int r = 0; r < 4; r++) {
      int row = rbase + r;
      if (row < N) {
        float v = acc[r] + bb;
        if (RELU) v = fmaxf(v, 0.f);
        if (OUTBF16) ((unsigned short*)Cout)[(size_t)row * OC + col] = f2bf(v);
        else         ((float*)Cout)[(size_t)row * OC + col] = v;
      }
    }
  }
}

// ---- SpMM (pull) dim=128 bf16: out[v] = s_in[v]*sum s_out[u]*x[u] -----
__global__ __launch_bounds__(256) void k_spmm128b(const unsigned short* __restrict__ x,
    const int* __restrict__ ebuf, const int* __restrict__ cnt,
    const float* __restrict__ sout, const float* __restrict__ sin_,
    unsigned short* __restrict__ out, int N) {
  int lane = threadIdx.x & 63;
  int v = blockIdx.x * 4 + (threadIdx.x >> 6);
  if (v >= N) return;
  v = __builtin_amdgcn_readfirstlane(v);
  int c = cnt[v]; c = c < MAXD ? c : MAXD;
  const int* el = ebuf + (size_t)v * MAXD;
  int u_l = 0; float w_l = 0.f;
  if (lane < c) { u_l = el[lane]; w_l = sout[u_l]; }
  float ax = 0.f, ay = 0.f;
  int i = 0;
  for (; i + 4 <= c; i += 4) {
    #pragma unroll
    for (int j = 0; j < 4; j++) {
      int u = __shfl(u_l, i + j);
      float w = __shfl(w_l, i + j);
      unsigned p = *(const unsigned*)(x + (size_t)u * 128 + lane * 2);
      float lo = __builtin_bit_cast(float, p << 16);
      float hi = __builtin_bit_cast(float, p & 0xFFFF0000u);
      ax = fmaf(w, lo, ax); ay = fmaf(w, hi, ay);
    }
  }
  for (; i < c; i++) {
    int u = __shfl(u_l, i);
    float w = __shfl(w_l, i);
    unsigned p = *(const unsigned*)(x + (size_t)u * 128 + lane * 2);
    float lo = __builtin_bit_cast(float, p << 16);
    float hi = __builtin_bit_cast(float, p & 0xFFFF0000u);
    ax = fmaf(w, lo, ax); ay = fmaf(w, hi, ay);
  }
  float sv = sin_[v];
  unsigned o = (unsigned)f2bf(sv * ax) | ((unsigned)f2bf(sv * ay) << 16);
  *(unsigned*)(out + (size_t)v * 128 + lane * 2) = o;
}

// ---- SpMM dim=128 bf16 + epilogue: +b2, split, z(bf16) ----------------
__global__ __launch_bounds__(256) void k_spmm2b(const unsigned short* __restrict__ hw,
    const int* __restrict__ ebuf, const int* __restrict__ cnt,
    const float* __restrict__ sout, const float* __restrict__ sin_,
    const float* __restrict__ b2, const float* __restrict__ eps,
    float* __restrict__ mean_out, float* __restrict__ logvar_out,
    unsigned short* __restrict__ z, int N) {
  int lane = threadIdx.x & 63;
  int v = blockIdx.x * 4 + (threadIdx.x >> 6);
  if (v >= N) return;
  v = __builtin_amdgcn_readfirstlane(v);
  int c = cnt[v]; c = c < MAXD ? c : MAXD;
  const int* el = ebuf + (size_t)v * MAXD;
  int u_l = 0; float w_l = 0.f;
  if (lane < c) { u_l = el[lane]; w_l = sout[u_l]; }
  float ax = 0.f, ay = 0.f;
  int i = 0;
  for (; i + 4 <= c; i += 4) {
    #pragma unroll
    for (int j = 0; j < 4; j++) {
      int u = __shfl(u_l, i + j);
      float w = __shfl(w_l, i + j);
      unsigned p = *(const unsigned*)(hw + (size_t)u * 128 + lane * 2);
      float lo = __builtin_bit_cast(float, p << 16);
      float hi = __builtin_bit_cast(float, p & 0xFFFF0000u);
      ax = fmaf(w, lo, ax); ay = fmaf(w, hi, ay);
    }
  }
  for (; i < c; i++) {
    int u = __shfl(u_l, i);
    float w = __shfl(w_l, i);
    unsigned p = *(const unsigned*)(hw + (size_t)u * 128 + lane * 2);
    float lo = __builtin_bit_cast(float, p << 16);
    float hi = __builtin_bit_cast(float, p & 0xFFFF0000u);
    ax = fmaf(w, lo, ax); ay = fmaf(w, hi, ay);
  }
  float sv = sin_[v];
  float2 bb = ((const float2*)b2)[lane];
  float mx = fmaf(sv, ax, bb.x);
  float my = fmaf(sv, ay, bb.y);
  // lanes 0..31: mean cols (2l,2l+1); lanes 32..63: logvar cols
  if (lane < 32) ((float2*)mean_out)[(size_t)v * 32 + lane] = make_float2(mx, my);
  else           ((float2*)logvar_out)[(size_t)v * 32 + (lane - 32)] = make_float2(mx, my);
  float lx = __shfl(mx, (lane & 31) + 32);
  float ly = __shfl(my, (lane & 31) + 32);
  if (lane < 32) {
    float2 e2 = ((const float2*)eps)[(size_t)v * 32 + lane];
    float zx = fmaf(e2.x, expf(0.5f * lx), mx);
    float zy = fmaf(e2.y, expf(0.5f * ly), my);
    unsigned o = (unsigned)f2bf(zx) | ((unsigned)f2bf(zy) << 16);
    *(unsigned*)(z + (size_t)v * 64 + lane * 2) = o;
  }
}

// ---- SpMM dim=64 bf16: aggz[v] = s_in[v]*sum s_out[u]*z[u] ------------
__global__ __launch_bounds__(256) void k_spmm64b(const unsigned short* __restrict__ z,
    const int* __restrict__ ebuf, const int* __restrict__ cnt,
    const float* __restrict__ sout, const float* __restrict__ sin_,
    unsigned short* __restrict__ aggz, int N) {
  int lane = threadIdx.x & 63;
  int v = blockIdx.x * 4 + (threadIdx.x >> 6);
  if (v >= N) return;
  v = __builtin_amdgcn_readfirstlane(v);
  int c = cnt[v]; c = c < MAXD ? c : MAXD;
  const int* el = ebuf + (size_t)v * MAXD;
  int u_l = 0; float w_l = 0.f;
  if (lane < c) { u_l = el[lane]; w_l = sout[u_l]; }
  float a = 0.f;
  int i = 0;
  for (; i + 8 <= c; i += 8) {
    #pragma unroll
    for (int j = 0; j < 8; j++) {
      int u = __shfl(u_l, i + j);
      float w = __shfl(w_l, i + j);
      a = fmaf(w, bf2f(z[(size_t)u * 64 + lane]), a);
    }
  }
  for (; i < c; i++) {
    int u = __shfl(u_l, i);
    float w = __shfl(w_l, i);
    a = fmaf(w, bf2f(z[(size_t)u * 64 + lane]), a);
  }
  aggz[(size_t)v * 64 + lane] = f2bf(sin_[v] * a);
}

extern "C" void kernel_launch(void* const* d_in, const int* in_sizes, int n_in,
                              void* d_out, int out_size, void* d_ws, size_t ws_size,
                              hipStream_t stream) {
  const float* features = (const float*)d_in[0];
  const int*   src      = (const int*)d_in[1];
  const int*   dst      = (const int*)d_in[2];
  const float* eps      = (const float*)d_in[3];
  const float* W1       = (const float*)d_in[4];
  const float* b1       = (const float*)d_in[5];
  const float* W2       = (const float*)d_in[6];
  const float* b2       = (const float*)d_in[7];
  const float* W3       = (const float*)d_in[8];
  const float* b3       = (const float*)d_in[9];
  const int E = in_sizes[1];
  const int N = in_sizes[3] / 64;   // eps is N x 64
  float* out = (float*)d_out;

  // workspace (~78 MB): two aliased N*256-byte feature regions
  char* ws = (char*)d_ws;
  int* degout = (int*)ws;            ws += (size_t)N * 4;
  int* cnt    = (int*)ws;            ws += (size_t)N * 4;
  int* ebuf   = (int*)ws;            ws += (size_t)N * MAXD * 4;
  float* sout = (float*)ws;          ws += (size_t)N * 4;
  float* sin_ = (float*)ws;          ws += (size_t)N * 4;
  short* W1p  = (short*)ws;          ws += 128 * 256 * 2;
  short* W2p  = (short*)ws;          ws += 256 * 128 * 2;
  short* W3p  = (short*)ws;          ws += 64 * 128 * 2;
  char* R1    = ws;                  ws += (size_t)N * 256;  // xb -> hwb -> aggz
  char* R2    = ws;                  ws += (size_t)N * 256;  // agg1 -> z(bf16)

  unsigned short* xb    = (unsigned short*)R1;  // N x 128 bf16
  unsigned short* hwb   = (unsigned short*)R1;  // N x 128 bf16 (xb dead)
  unsigned short* aggzb = (unsigned short*)R1;  // N x 64  bf16 (hwb dead)
  unsigned short* agg1b = (unsigned short*)R2;  // N x 128 bf16
  unsigned short* zb    = (unsigned short*)R2;  // N x 64  bf16 (agg1 dead)

  // h (N x 256 bf16 = 51.2MB) lives in out[0..128N) floats; dead before recon
  unsigned short* h     = (unsigned short*)out;
  float* recon          = out;
  float* mean_out       = out + (size_t)N * 128;
  float* logvar_out     = out + (size_t)N * 192;

  hipMemsetAsync(degout, 0, (size_t)N * 8, stream);  // degout + cnt

  int bps = ((E + 3) / 4 + 255) / 256;   // blocks per slice
  k_hist_sl<<<bps * 8, 256, 0, stream>>>(src, dst, degout, cnt, ebuf, E);
  k_sortel<<<(N + 3) / 4, 256, 0, stream>>>(ebuf, cnt, N);
  k_scale<<<(N + 255) / 256, 256, 0, stream>>>(degout, cnt, sout, sin_, N);
  k_cvt<<<((N * 128 / 4) + 255) / 256, 256, 0, stream>>>(features, xb, N * 128);
  k_wrepack<128, 256><<<16, 256, 0, stream>>>(W1, W1p);
  k_wrepack<256, 128><<<16, 256, 0, stream>>>(W2, W2p);
  k_wrepack<64, 128><<<4, 256, 0, stream>>>(W3, W3p);

  // gconv1: SpMM(xb) -> agg1b; MFMA GEMM 128->256 +b1, relu -> h (bf16)
  k_spmm128b<<<(N + 3) / 4, 256, 0, stream>>>(xb, ebuf, cnt, sout, sin_, agg1b, N);
  k_gemm_mfma<128, 256, true, true, true>
      <<<(N + 63) / 64, 256, 0, stream>>>(agg1b, W1p, b1, h, N);

  // gconv2: MFMA GEMM 256->128 (h @ W2 -> hwb), then SpMM +b2, split, z(bf16)
  k_gemm_mfma<256, 128, false, false, true>
      <<<(N + 63) / 64, 256, 0, stream>>>(h, W2p, nullptr, hwb, N);
  k_spmm2b<<<(N + 3) / 4, 256, 0, stream>>>(hwb, ebuf, cnt, sout, sin_, b2, eps,
                                            mean_out, logvar_out, zb, N);

  // gconv3: SpMM(zb) -> aggzb (bf16); MFMA GEMM 64->128 +b3 -> recon
  k_spmm64b<<<(N + 3) / 4, 256, 0, stream>>>(zb, ebuf, cnt, sout, sin_, aggzb, N);
  k_gemm_mfma<64, 128, false, true, false>
      <<<(N + 63) / 64, 256, 0, stream>>>(aggzb, W3p, b3, recon, N);
}